// Round 17
// baseline (81.472 us; speedup 1.0000x reference)
//
#include <hip/hip_runtime.h>

#define B_   16
#define C_   512
#define HW_  1024
#define S_   77
#define CTX_ 768
#define HEADS_ 8
#define G_   8
#define EPS_ 1e-5f

typedef unsigned short u16;
typedef unsigned int u32;
typedef __attribute__((ext_vector_type(8))) short bfx8;   // 8 bf16 MFMA A/B frag
typedef __attribute__((ext_vector_type(4))) float fx4;    // MFMA C/D frag

union U2 { u16 h[4]; uint2 v; };

__device__ __forceinline__ u16 f2bf(float f) {
  union { float f; u32 u; } v; v.f = f;
  u32 u = v.u;
  return (u16)((u + 0x7FFFu + ((u >> 16) & 1u)) >> 16);
}
__device__ __forceinline__ float bf2f(u16 h) {
  union { u32 u; float f; } v; v.u = ((u32)h) << 16;
  return v.f;
}

// async global->LDS, 16B per lane (lane-linear LDS dest, per-lane global src)
__device__ __forceinline__ void gload16(const u16* g, u16* l) {
  __builtin_amdgcn_global_load_lds((const __attribute__((address_space(1))) u32*)g,
                                   (__attribute__((address_space(3))) u32*)l, 16, 0, 0);
}

// ---------------- prep bodies ----------------
// weight cast f32 -> bf16, row-swizzled: out[m][k] at m*K + (k&~63) + (((k%64)/8 ^ (m&7))*8) + (k&7)
__device__ __forceinline__ void castw_body(const float* __restrict__ in,
                                           u16* __restrict__ out, int K, int i, int n4) {
  if (i >= n4) return;
  float4 v = *(const float4*)(in + (size_t)i * 4);
  int K4 = K >> 2;
  int m = i / K4;
  int k = (i - m * K4) * 4;
  int pb = ((k & 63) >> 3) ^ (m & 7);
  size_t dst = (size_t)m * K + (k & ~63) + (pb << 3) + (k & 7);
  U2 pk;
  pk.h[0] = f2bf(v.x); pk.h[1] = f2bf(v.y); pk.h[2] = f2bf(v.z); pk.h[3] = f2bf(v.w);
  *(uint2*)(out + dst) = pk.v;
}

__device__ __forceinline__ void castctx_body(const float* __restrict__ in,
                                             u16* __restrict__ out, int i) {
  if (i >= 16 * 77 * 192) return;
  int rg = i / 192;
  int k = (i - rg * 192) * 4;
  int b = rg / 77, s = rg - b * 77;
  float4 v = *(const float4*)(in + (size_t)i * 4);
  int pb = ((k & 63) >> 3) ^ (s & 7);
  size_t dst = ((size_t)b * 128 + s) * 768 + (k & ~63) + (pb << 3) + (k & 7);
  U2 pk;
  pk.h[0] = f2bf(v.x); pk.h[1] = f2bf(v.y); pk.h[2] = f2bf(v.z); pk.h[3] = f2bf(v.w);
  *(uint2*)(out + dst) = pk.v;
}

// GN transpose + stats (single x pass): blk in [0,1024) = bg*8 + nt.
// Reads x tile f32 once, accumulates partial (sum, sumsq) -> part[blk],
// writes RAW bf16 transposed+swizzled tile into hT (affine applied later in-place).
__device__ void gntrans_body(int blk, const float* __restrict__ x,
                             u16* __restrict__ hT, float2* __restrict__ part,
                             u16* __restrict__ T2, float* rs, float* rss) {
  int t = threadIdx.x;
  int nt = blk & 7, bg = blk >> 3;
  int batch = bg >> 3, g = bg & 7;
  const float4* x4 = (const float4*)(x + ((size_t)batch * C_ + (size_t)g * 64) * HW_);
  int n4i = t & 31;
  int c4b = t >> 5;
  float s = 0.f, ss = 0.f;
  #pragma unroll
  for (int j = 0; j < 2; ++j) {
    int c4 = c4b + j * 8;
    float4 v[4];
    #pragma unroll
    for (int e = 0; e < 4; ++e) {
      v[e] = x4[(size_t)(c4 * 4 + e) * 256 + nt * 32 + n4i];
      s  += v[e].x + v[e].y + v[e].z + v[e].w;
      ss += v[e].x*v[e].x + v[e].y*v[e].y + v[e].z*v[e].z + v[e].w*v[e].w;
    }
    int cbase = c4 * 4;
    #pragma unroll
    for (int ne = 0; ne < 4; ++ne) {
      int n = n4i * 4 + ne;
      int pb = (cbase >> 3) ^ (n & 7);
      U2 pk;
      pk.h[0] = f2bf(((const float*)&v[0])[ne]);
      pk.h[1] = f2bf(((const float*)&v[1])[ne]);
      pk.h[2] = f2bf(((const float*)&v[2])[ne]);
      pk.h[3] = f2bf(((const float*)&v[3])[ne]);
      *(uint2*)&T2[n * 72 + (pb << 3) + (cbase & 7)] = pk.v;
    }
  }
  #pragma unroll
  for (int off = 32; off; off >>= 1) {
    s  += __shfl_down(s, off);
    ss += __shfl_down(ss, off);
  }
  int wid = t >> 6;
  if ((t & 63) == 0) { rs[wid] = s; rss[wid] = ss; }
  __syncthreads();   // T2 complete + rs/rss visible
  if (t == 0)
    part[blk] = make_float2(rs[0] + rs[1] + rs[2] + rs[3],
                            rss[0] + rss[1] + rss[2] + rss[3]);
  #pragma unroll
  for (int j = 0; j < 4; ++j) {
    int idx = j * 256 + t;
    int row = idx >> 3, cs = (idx & 7) * 8;
    uint4 vv = *(const uint4*)&T2[row * 72 + cs];
    *(uint4*)(hT + ((size_t)batch * 1024 + nt * 128 + row) * 512 + g * 64 + cs) = vv;
  }
}

// ---------------- fused prep: weight/ctx casts + GN transpose+stats ----------------
__global__ __launch_bounds__(256) void prep_kernel(const float* __restrict__ q_w,
                                                   const float* __restrict__ kv_w,
                                                   const float* __restrict__ proj_w,
                                                   const float* __restrict__ ctx,
                                                   const float* __restrict__ x,
                                                   u16* __restrict__ qw_bf,
                                                   u16* __restrict__ kvw_bf,
                                                   u16* __restrict__ pjw_bf,
                                                   u16* __restrict__ ctx_bf,
                                                   u16* __restrict__ hT,
                                                   float2* __restrict__ gpart) {
  __shared__ u16 T2[9216];
  __shared__ float rs[4], rss[4];
  int bid = blockIdx.x, t = threadIdx.x;
  if (bid < 256)        castw_body(q_w,    qw_bf,  512, bid * 256 + t, 65536);
  else if (bid < 1024)  castw_body(kv_w,   kvw_bf, 768, (bid - 256) * 256 + t, 196608);
  else if (bid < 1280)  castw_body(proj_w, pjw_bf, 512, (bid - 1024) * 256 + t, 65536);
  else if (bid < 2204)  castctx_body(ctx, ctx_bf, (bid - 1280) * 256 + t);
  else                  gntrans_body(bid - 2204, x, hT, gpart, T2, rs, rss);
}

// ---------------- GN affine body: in-place RMW on hT (raw bf16 -> normalized) ----------------
// blk in [0,1024) = bg*8 + nt. Channel of stored elem: c = ((jb ^ (row&7))<<3)+e
// (inverse of producer's pb = (c>>3) ^ (n&7)).
__device__ void gnaff_body(int blk, const float* __restrict__ w,
                           const float* __restrict__ bgn,
                           const float2* __restrict__ gpart,
                           u16* __restrict__ hT, float* tab) {
  int t = threadIdx.x;
  int nt = blk & 7, bg = blk >> 3;
  int batch = bg >> 3, g = bg & 7;
  float s = 0.f, ss = 0.f;
  #pragma unroll
  for (int j = 0; j < 8; ++j) { float2 pp = gpart[bg * 8 + j]; s += pp.x; ss += pp.y; }
  const float invN = 1.0f / 65536.0f;
  float mean = s * invN;
  float rstd = rsqrtf(ss * invN - mean * mean + EPS_);
  if (t < 64) {
    float wc = w[g * 64 + t] * rstd;
    tab[t] = wc;
    tab[64 + t] = bgn[g * 64 + t] - mean * wc;
  }
  __syncthreads();
  u16* base = hT + ((size_t)batch * 1024 + (size_t)nt * 128) * 512 + g * 64;
  #pragma unroll
  for (int j = 0; j < 4; ++j) {
    int idx = j * 256 + t;
    int row = idx >> 3, jb = idx & 7;
    u16* pp = base + (size_t)row * 512 + jb * 8;
    uint4 v = *(const uint4*)pp;
    const u16* hv = (const u16*)&v;
    int ch = (jb ^ (row & 7)) << 3;
    U2 lo, hi;
    #pragma unroll
    for (int e = 0; e < 4; ++e)
      lo.h[e] = f2bf(bf2f(hv[e]) * tab[ch + e] + tab[64 + ch + e]);
    #pragma unroll
    for (int e = 0; e < 4; ++e)
      hi.h[e] = f2bf(bf2f(hv[4 + e]) * tab[ch + 4 + e] + tab[64 + ch + 4 + e]);
    uint4 o; o.x = lo.v.x; o.y = lo.v.y; o.z = hi.v.x; o.w = hi.v.y;
    *(uint4*)pp = o;
  }
}

// ---------------- KV GEMM body, 64x32 tiles ----------------
// blk in [0,1024): b = blk>>6, m0 = ((blk>>5)&1)*64, n0 = (blk&31)*32
__device__ void kvgemm_body(int blk, const u16* __restrict__ A, const u16* __restrict__ Bw,
                            const float* __restrict__ bias,
                            u16* __restrict__ o16a, u16* __restrict__ o16b,
                            u16* __restrict__ SH) {
  u16* As = SH;            // 64*64
  u16* Bs = SH + 4096;     // 32*64
  int t = threadIdx.x;
  int b = blk >> 6;
  int m0 = ((blk >> 5) & 1) * 64;
  int n0 = (blk & 31) * 32;
  const u16* aBase = A + (size_t)b * 98304 + (size_t)(m0 + (t >> 3)) * 768 + (t & 7) * 8;
  const u16* bBase = Bw + (size_t)(n0 + (t >> 3)) * 768 + (t & 7) * 8;
  int wid = t >> 6, l = t & 63;
  int wr = wid & 1, wc = wid >> 1;
  int lr = l & 15, lg = l >> 4, xr = lr & 7;
  fx4 acc[2];
  acc[0] = (fx4){0.f, 0.f, 0.f, 0.f};
  acc[1] = (fx4){0.f, 0.f, 0.f, 0.f};

  for (int k0 = 0; k0 < 768; k0 += 64) {
    __syncthreads();
    #pragma unroll
    for (int i = 0; i < 2; ++i)
      gload16(aBase + k0 + (size_t)i * 32 * 768, As + i * 2048 + t * 8);
    gload16(bBase + k0, Bs + t * 8);
    __syncthreads();
    #pragma unroll
    for (int kk = 0; kk < 2; ++kk) {
      int lb = kk * 4 + lg;
      bfx8 bf = *(const bfx8*)&Bs[(wc * 16 + lr) * 64 + ((lb ^ xr) << 3)];
      #pragma unroll
      for (int mi = 0; mi < 2; ++mi) {
        bfx8 af = *(const bfx8*)&As[(wr * 32 + mi * 16 + lr) * 64 + ((lb ^ xr) << 3)];
        acc[mi] = __builtin_amdgcn_mfma_f32_16x16x32_bf16(af, bf, acc[mi], 0, 0, 0);
      }
    }
  }

  int o = n0 + wc * 16 + lr;
  float bb = bias[o];
  #pragma unroll
  for (int mi = 0; mi < 2; ++mi) {
    int sb = m0 + wr * 32 + mi * 16 + lg * 4;
    if (o < 512) {
      #pragma unroll
      for (int r = 0; r < 4; ++r) {
        int sidx = sb + r;
        if (sidx < 96) {
          int ob = (o & ~63) | (((((o >> 3) & 7) ^ (sidx & 7))) << 3) | (o & 7);
          o16a[(size_t)b * 49152 + (size_t)sidx * 512 + ob] = f2bf(acc[mi][r] + bb);
        }
      }
    } else if (sb < 96) {
      U2 pk;
      #pragma unroll
      for (int r = 0; r < 4; ++r)
        pk.h[r] = (sb + r < S_) ? f2bf(acc[mi][r] + bb) : (u16)0;
      *(uint2*)(o16b + (size_t)b * 49152 + (size_t)(o - 512) * 96 + sb) = pk.v;
    }
  }
}

// ---------------- merged mid kernel: gn affine RMW (blocks 0-1023) + kvgemm (1024-2047) ----------------
__global__ __launch_bounds__(256) void mid_kernel(const float* __restrict__ gn_w,
                                                  const float* __restrict__ gn_b,
                                                  const float2* __restrict__ gpart,
                                                  u16* __restrict__ hT,
                                                  const u16* __restrict__ ctx_bf,
                                                  const u16* __restrict__ kvw_bf,
                                                  const float* __restrict__ kv_b,
                                                  u16* __restrict__ kvT_k,
                                                  u16* __restrict__ kvV) {
  __shared__ u16 SH[6144];   // kv: As 4096 + Bs 2048; gn: 128-float table (512B) at front
  int bid = blockIdx.x;
  if (bid < 1024) gnaff_body(bid, gn_w, gn_b, gpart, hT, (float*)SH);
  else            kvgemm_body(bid - 1024, ctx_bf, kvw_bf, kv_b, kvT_k, kvV, SH);
}

// ---------------- proj GEMM: 128x128, f32 out + residual (R10-proven) ----------------
__global__ __launch_bounds__(256) void gemm2_kernel(
    const u16* __restrict__ A, const u16* __restrict__ Bw,
    const float* __restrict__ bias, const float* __restrict__ resid,
    float* __restrict__ outf, int K, size_t strideA)
{
  __shared__ u16 As[128 * 64];
  __shared__ u16 Bs[128 * 64];
  int t = threadIdx.x;
  int b = blockIdx.z;
  int n0 = blockIdx.x * 128, m0 = blockIdx.y * 128;
  const u16* aBase = A + (size_t)b * strideA + (size_t)(m0 + (t >> 3)) * K + (t & 7) * 8;
  const u16* bBase = Bw + (size_t)(n0 + (t >> 3)) * K + (t & 7) * 8;
  int wid = t >> 6, l = t & 63;
  int wr = wid >> 1, wc = wid & 1;
  int lr = l & 15, lg = l >> 4;
  fx4 acc[4][4];
  #pragma unroll
  for (int i = 0; i < 4; ++i)
    #pragma unroll
    for (int j = 0; j < 4; ++j) acc[i][j] = (fx4){0.f, 0.f, 0.f, 0.f};

  for (int k0 = 0; k0 < K; k0 += 64) {
    __syncthreads();
    #pragma unroll
    for (int i = 0; i < 4; ++i) {
      gload16(aBase + k0 + (size_t)i * 32 * K, As + i * 2048 + t * 8);
      gload16(bBase + k0 + (size_t)i * 32 * K, Bs + i * 2048 + t * 8);
    }
    __syncthreads();
    #pragma unroll
    for (int kk = 0; kk < 2; ++kk) {
      bfx8 af[4], bf[4];
      int xr = (lr & 7);
      #pragma unroll
      for (int i = 0; i < 4; ++i) {
        int lb = kk * 4 + lg;
        af[i] = *(const bfx8*)&As[(wr * 64 + i * 16 + lr) * 64 + ((lb ^ xr) << 3)];
        bf[i] = *(const bfx8*)&Bs[(wc * 64 + i * 16 + lr) * 64 + ((lb ^ xr) << 3)];
      }
      #pragma unroll
      for (int mi = 0; mi < 4; ++mi)
        #pragma unroll
        for (int ni = 0; ni < 4; ++ni)
          acc[mi][ni] = __builtin_amdgcn_mfma_f32_16x16x32_bf16(af[mi], bf[ni], acc[mi][ni], 0, 0, 0);
    }
  }

  float* O = outf + (size_t)b * 524288;
  const float* R = resid + (size_t)b * 524288;
  #pragma unroll
  for (int ni = 0; ni < 4; ++ni) {
    int cc = n0 + wc * 64 + ni * 16 + lr;
    float bb = bias[cc];
    #pragma unroll
    for (int mi = 0; mi < 4; ++mi) {
      size_t off = (size_t)cc * 1024 + m0 + wr * 64 + mi * 16 + lg * 4;
      float4 rv = *(const float4*)(R + off);
      float4 ov;
      ov.x = acc[mi][ni][0] + bb + rv.x;
      ov.y = acc[mi][ni][1] + bb + rv.y;
      ov.z = acc[mi][ni][2] + bb + rv.z;
      ov.w = acc[mi][ni][3] + bb + rv.w;
      *(float4*)(O + off) = ov;
    }
  }
}

// ---------------- fused Q-GEMM (LDS-staged) + attention (direct K/V), 64-q blocks ----------------
// hT: [b][n][512] swz; qw: [512][512] swz; kvK: [b][96][512] swz; kvV: [b][512][96] plain
// aoT out: [b][n][512] swz. LDS: QO 8KB + union{As 8KB + Bs 8KB, Ps 13.3KB} = 24KB -> 6 blocks/CU.
__global__ __launch_bounds__(256) void qattn_kernel(const u16* __restrict__ hT,
                                                    const u16* __restrict__ qw,
                                                    const float* __restrict__ q_b,
                                                    const u16* __restrict__ kvK,
                                                    const u16* __restrict__ kvV,
                                                    u16* __restrict__ aoT) {
  __shared__ u16 SH[12288];
  u16* QO = SH;                  // 64*64
  u16* As = SH + 4096;           // 64*64 staging (Q-GEMM phase)
  u16* Bs = SH + 8192;           // 64*64 staging
  u16* Ps = SH + 4096;           // 64*104 softmax weights (after Q-GEMM)

  int t = threadIdx.x;
  int n0 = blockIdx.x * 64, head = blockIdx.y, b = blockIdx.z;
  int wid = t >> 6, l = t & 63;
  int lr = l & 15, lg = l >> 4, xr = lr & 7;
  int qbase = wid * 16;

  // ---- Q-GEMM: QO[64 q][64 d] = hT[n0+q][:] . qw[head*64+d][:] + q_b (LDS-staged) ----
  {
    const u16* aBase = hT + (size_t)b * 524288 + (size_t)(n0 + (t >> 3)) * 512 + (t & 7) * 8;
    const u16* bBase = qw + (size_t)(head * 64 + (t >> 3)) * 512 + (t & 7) * 8;
    fx4 acc[4];
    #pragma unroll
    for (int j = 0; j < 4; ++j) acc[j] = (fx4){0.f, 0.f, 0.f, 0.f};
    for (int k0 = 0; k0 < 512; k0 += 64) {
      __syncthreads();
      #pragma unroll
      for (int i = 0; i < 2; ++i) {
        gload16(aBase + k0 + (size_t)i * 32 * 512, As + i * 2048 + t * 8);
        gload16(bBase + k0 + (size_t)i * 32 * 512, Bs + i * 2048 + t * 8);
      }
      __syncthreads();
      #pragma unroll
      for (int kk = 0; kk < 2; ++kk) {
        int lb = kk * 4 + lg;
        bfx8 af = *(const bfx8*)&As[(qbase + lr) * 64 + ((lb ^ xr) << 3)];
        bfx8 bf[4];
        #pragma unroll
        for (int i = 0; i < 4; ++i)
          bf[i] = *(const bfx8*)&Bs[(i * 16 + lr) * 64 + ((lb ^ xr) << 3)];
        #pragma unroll
        for (int ni = 0; ni < 4; ++ni)
          acc[ni] = __builtin_amdgcn_mfma_f32_16x16x32_bf16(af, bf[ni], acc[ni], 0, 0, 0);
      }
    }
    // scatter D+bias into QO (swizzled [q][d]); own-wave rows only
    #pragma unroll
    for (int ni = 0; ni < 4; ++ni) {
      int d = ni * 16 + lr;
      float bb = q_b[head * 64 + d];
      #pragma unroll
      for (int r = 0; r < 4; ++r) {
        int q = qbase + lg * 4 + r;
        QO[q * 64 + ((((d >> 3) ^ (q & 7))) << 3) + (d & 7)] = f2bf(acc[ni][r] + bb);
      }
    }
  }
  __syncthreads();   // all waves done reading As/Bs -> Ps region usable

  // ---- zero Ps pad cols [80,96) for own-wave rows ----
  {
    int row = qbase + (l >> 2), part = l & 3;
    if (part < 2)
      *(uint4*)&Ps[row * 104 + 80 + part * 8] = (uint4){0u, 0u, 0u, 0u};
  }

  // ---- QK^T + softmax + P (K direct from global, L1/L2-resident slice) ----
  const u16* kB = kvK + (size_t)b * 49152 + head * 64;
  {
    int qrow = qbase + lr;
    fx4 sc[5];
    #pragma unroll
    for (int ti = 0; ti < 5; ++ti) sc[ti] = (fx4){0.f, 0.f, 0.f, 0.f};
    #pragma unroll
    for (int ks = 0; ks < 2; ++ks) {
      int kb = ((ks * 4 + lg) ^ xr) << 3;
      bfx8 a = *(const bfx8*)&QO[qrow * 64 + kb];
      #pragma unroll
      for (int ti = 0; ti < 5; ++ti) {
        bfx8 bb = *(const bfx8*)(kB + (size_t)(ti * 16 + lr) * 512 + kb);
        sc[ti] = __builtin_amdgcn_mfma_f32_16x16x32_bf16(a, bb, sc[ti], 0, 0, 0);
      }
    }
    #pragma unroll
    for (int ti = 0; ti < 5; ++ti) {
      bool valid = (ti * 16 + lr) < S_;
      #pragma unroll
      for (int r = 0; r < 4; ++r)
        sc[ti][r] = valid ? sc[ti][r] * 0.125f : -1e30f;
    }
    fx4 mx = sc[0];
    #pragma unroll
    for (int ti = 1; ti < 5; ++ti)
      #pragma unroll
      for (int r = 0; r < 4; ++r) mx[r] = fmaxf(mx[r], sc[ti][r]);
    #pragma unroll
    for (int off = 1; off < 16; off <<= 1)
      #pragma unroll
      for (int r = 0; r < 4; ++r) mx[r] = fmaxf(mx[r], __shfl_xor(mx[r], off));
    fx4 sm = (fx4){0.f, 0.f, 0.f, 0.f};
    #pragma unroll
    for (int ti = 0; ti < 5; ++ti)
      #pragma unroll
      for (int r = 0; r < 4; ++r) {
        float e = __expf(sc[ti][r] - mx[r]);
        sc[ti][r] = e; sm[r] += e;
      }
    #pragma unroll
    for (int off = 1; off < 16; off <<= 1)
      #pragma unroll
      for (int r = 0; r < 4; ++r) sm[r] += __shfl_xor(sm[r], off);
    fx4 inv;
    #pragma unroll
    for (int r = 0; r < 4; ++r) inv[r] = __builtin_amdgcn_rcpf(sm[r]);
    #pragma unroll
    for (int ti = 0; ti < 5; ++ti)
      #pragma unroll
      for (int r = 0; r < 4; ++r)
        Ps[(qbase + lg * 4 + r) * 104 + ti * 16 + lr] = f2bf(sc[ti][r] * inv[r]);
  }

  // ---- PV (A = V direct from global [d][96], B = P from LDS) -> D[d][q] ----
  const u16* vB = kvV + (size_t)b * 49152 + (size_t)head * 64 * 96;
  {
    int q = qbase + lr;
    fx4 o[4];
    #pragma unroll
    for (int dt = 0; dt < 4; ++dt) o[dt] = (fx4){0.f, 0.f, 0.f, 0.f};
    #pragma unroll
    for (int ks = 0; ks < 3; ++ks) {
      bfx8 pb_ = *(const bfx8*)&Ps[q * 104 + ks * 32 + lg * 8];
      #pragma unroll
      for (int dt = 0; dt < 4; ++dt) {
        bfx8 a = *(const bfx8*)(vB + (size_t)(dt * 16 + lr) * 96 + ks * 32 + lg * 8);
        o[dt] = __builtin_amdgcn_mfma_f32_16x16x32_bf16(a, pb_, o[dt], 0, 0, 0);
      }
    }
    #pragma unroll
    for (int dt = 0; dt < 4; ++dt) {
      int db = dt * 16 + lg * 4;
      int pb = ((db >> 3) ^ (q & 7));
      U2 pk;
      #pragma unroll
      for (int r = 0; r < 4; ++r) pk.h[r] = f2bf(o[dt][r]);
      *(uint2*)&QO[q * 64 + (pb << 3) + (db & 7)] = pk.v;
    }
  }
  __syncthreads();

  const size_t aobase = (size_t)b * 524288 + (size_t)n0 * 512 + head * 64;
  #pragma unroll
  for (int j = 0; j < 2; ++j) {
    int idx = j * 256 + t;
    int row = idx >> 3, cs = (idx & 7) * 8;
    *(uint4*)(aoT + aobase + (size_t)row * 512 + cs) = *(const uint4*)&QO[row * 64 + cs];
  }
}

extern "C" void kernel_launch(void* const* d_in, const int* in_sizes, int n_in,
                              void* d_out, int out_size, void* d_ws, size_t ws_size,
                              hipStream_t stream) {
  const float* x      = (const float*)d_in[0];
  const float* ctx    = (const float*)d_in[1];
  const float* gn_w   = (const float*)d_in[2];
  const float* gn_b   = (const float*)d_in[3];
  const float* q_w    = (const float*)d_in[4];
  const float* q_b    = (const float*)d_in[5];
  const float* kv_w   = (const float*)d_in[6];
  const float* kv_b   = (const float*)d_in[7];
  const float* proj_w = (const float*)d_in[8];
  const float* proj_b = (const float*)d_in[9];
  float* out = (float*)d_out;

  u16* p = (u16*)d_ws;
  u16* qw_bf  = p; p += 262144;          // 512*512
  u16* kvw_bf = p; p += 786432;          // 1024*768
  u16* pjw_bf = p; p += 262144;          // 512*512
  u16* ctx_bf = p; p += 16 * 128 * 768;  // padded rows
  u16* hT     = p; p += 8388608;         // 16*1024*512
  u16* aoT    = p; p += 8388608;         // 16*1024*512
  u16* kvT_k  = p; p += 16 * 96 * 512;
  u16* kvV    = p; p += 16 * 512 * 96;   // V [d][96], zero-padded
  float2* gpart = (float2*)p; p += 1024 * 4;

  // 1) fused prep: 3 weight casts + ctx cast + GN transpose+stats (single x pass)
  prep_kernel<<<3228, 256, 0, stream>>>(q_w, kv_w, proj_w, ctx, x,
                                        qw_bf, kvw_bf, pjw_bf, ctx_bf, hT, gpart);

  // 2) merged: GN affine RMW (blocks 0-1023) + KV GEMM (blocks 1024-2047)
  mid_kernel<<<2048, 256, 0, stream>>>(gn_w, gn_b, gpart, hT,
                                       ctx_bf, kvw_bf, kv_b, kvT_k, kvV);

  // 3) fused Q-GEMM (staged) + attention (direct K/V), 64-q blocks for occupancy
  qattn_kernel<<<dim3(16, HEADS_, B_), 256, 0, stream>>>(hT, qw_bf, q_b, kvT_k, kvV, aoT);

  // 4) proj: 128x128 -> f32 out + residual
  gemm2_kernel<<<dim3(4, 8, B_), 256, 0, stream>>>(
      aoT, pjw_bf, proj_b, x, out, 512, (size_t)1024 * 512);
}

// Round 18
// 79.407 us; speedup vs baseline: 1.0260x; 1.0260x over previous
//
#include <hip/hip_runtime.h>

#define B_   16
#define C_   512
#define HW_  1024
#define S_   77
#define CTX_ 768
#define HEADS_ 8
#define G_   8
#define EPS_ 1e-5f

typedef unsigned short u16;
typedef unsigned int u32;
typedef __attribute__((ext_vector_type(8))) short bfx8;   // 8 bf16 MFMA A/B frag
typedef __attribute__((ext_vector_type(4))) float fx4;    // MFMA C/D frag

union U2 { u16 h[4]; uint2 v; };

__device__ __forceinline__ u16 f2bf(float f) {
  union { float f; u32 u; } v; v.f = f;
  u32 u = v.u;
  return (u16)((u + 0x7FFFu + ((u >> 16) & 1u)) >> 16);
}

// async global->LDS, 16B per lane (lane-linear LDS dest, per-lane global src)
__device__ __forceinline__ void gload16(const u16* g, u16* l) {
  __builtin_amdgcn_global_load_lds((const __attribute__((address_space(1))) u32*)g,
                                   (__attribute__((address_space(3))) u32*)l, 16, 0, 0);
}

// ---------------- prep bodies ----------------
// weight cast f32 -> bf16, row-swizzled: out[m][k] at m*K + (k&~63) + (((k%64)/8 ^ (m&7))*8) + (k&7)
__device__ __forceinline__ void castw_body(const float* __restrict__ in,
                                           u16* __restrict__ out, int K, int i, int n4) {
  if (i >= n4) return;
  float4 v = *(const float4*)(in + (size_t)i * 4);
  int K4 = K >> 2;
  int m = i / K4;
  int k = (i - m * K4) * 4;
  int pb = ((k & 63) >> 3) ^ (m & 7);
  size_t dst = (size_t)m * K + (k & ~63) + (pb << 3) + (k & 7);
  U2 pk;
  pk.h[0] = f2bf(v.x); pk.h[1] = f2bf(v.y); pk.h[2] = f2bf(v.z); pk.h[3] = f2bf(v.w);
  *(uint2*)(out + dst) = pk.v;
}

__device__ __forceinline__ void castctx_body(const float* __restrict__ in,
                                             u16* __restrict__ out, int i) {
  if (i >= 16 * 77 * 192) return;
  int rg = i / 192;
  int k = (i - rg * 192) * 4;
  int b = rg / 77, s = rg - b * 77;
  float4 v = *(const float4*)(in + (size_t)i * 4);
  int pb = ((k & 63) >> 3) ^ (s & 7);
  size_t dst = ((size_t)b * 128 + s) * 768 + (k & ~63) + (pb << 3) + (k & 7);
  U2 pk;
  pk.h[0] = f2bf(v.x); pk.h[1] = f2bf(v.y); pk.h[2] = f2bf(v.z); pk.h[3] = f2bf(v.w);
  *(uint2*)(out + dst) = pk.v;
}

__device__ __forceinline__ void gnstats_body(const float* __restrict__ x,
                                             float2* __restrict__ part, int blk, int t) {
  int bg = blk >> 3, slice = blk & 7;
  const float4* x4 = (const float4*)(x + (size_t)bg * 65536);
  float s = 0.f, ss = 0.f;
  #pragma unroll
  for (int j = 0; j < 8; ++j) {
    float4 v = x4[slice * 2048 + j * 256 + t];
    s  += v.x + v.y + v.z + v.w;
    ss += v.x*v.x + v.y*v.y + v.z*v.z + v.w*v.w;
  }
  #pragma unroll
  for (int off = 32; off; off >>= 1) {
    s  += __shfl_down(s, off);
    ss += __shfl_down(ss, off);
  }
  __shared__ float rs[4], rss[4];
  int wid = t >> 6;
  if ((t & 63) == 0) { rs[wid] = s; rss[wid] = ss; }
  __syncthreads();
  if (t == 0)
    part[blk] = make_float2(rs[0] + rs[1] + rs[2] + rs[3],
                            rss[0] + rss[1] + rss[2] + rss[3]);
}

// ---------------- fused prep: weight/ctx casts + GN partial sums ----------------
__global__ __launch_bounds__(256) void prep_kernel(const float* __restrict__ q_w,
                                                   const float* __restrict__ kv_w,
                                                   const float* __restrict__ proj_w,
                                                   const float* __restrict__ ctx,
                                                   const float* __restrict__ x,
                                                   u16* __restrict__ qw_bf,
                                                   u16* __restrict__ kvw_bf,
                                                   u16* __restrict__ pjw_bf,
                                                   u16* __restrict__ ctx_bf,
                                                   float2* __restrict__ gpart) {
  int bid = blockIdx.x, t = threadIdx.x;
  if (bid < 256)        castw_body(q_w,    qw_bf,  512, bid * 256 + t, 65536);
  else if (bid < 1024)  castw_body(kv_w,   kvw_bf, 768, (bid - 256) * 256 + t, 196608);
  else if (bid < 1280)  castw_body(proj_w, pjw_bf, 512, (bid - 1024) * 256 + t, 65536);
  else if (bid < 2204)  castctx_body(ctx, ctx_bf, (bid - 1280) * 256 + t);
  else                  gnstats_body(x, gpart, bid - 2204, t);
}

// ---------------- GroupNorm apply body (stats folded inline) -> h^T swizzled ----------------
__device__ void gn_apply_body(int blk, const float* __restrict__ x,
                              const float* __restrict__ w,
                              const float* __restrict__ bgn,
                              const float2* __restrict__ gpart,
                              u16* __restrict__ hT, u16* __restrict__ T2) {
  int nt = blk & 7, bg = blk >> 3;
  int batch = bg >> 3, g = bg & 7;
  const float4* x4 = (const float4*)(x + ((size_t)batch * C_ + (size_t)g * 64) * HW_);
  float s = 0.f, ss = 0.f;
  #pragma unroll
  for (int j = 0; j < 8; ++j) { float2 pp = gpart[bg * 8 + j]; s += pp.x; ss += pp.y; }
  const float invN = 1.0f / 65536.0f;
  float mean = s * invN;
  float rstd = rsqrtf(ss * invN - mean * mean + EPS_);
  int t = threadIdx.x;
  int n4i = t & 31;
  int c4b = t >> 5;
  #pragma unroll
  for (int j = 0; j < 2; ++j) {
    int c4 = c4b + j * 8;
    float4 v[4];
    float wcs[4], bcs[4];
    #pragma unroll
    for (int e = 0; e < 4; ++e) {
      int c = c4 * 4 + e;
      v[e] = x4[(size_t)c * 256 + nt * 32 + n4i];
      int cg = g * 64 + c;
      float wc_ = w[cg] * rstd;
      wcs[e] = wc_;
      bcs[e] = bgn[cg] - mean * wc_;
    }
    int cbase = c4 * 4;
    #pragma unroll
    for (int ne = 0; ne < 4; ++ne) {
      int n = n4i * 4 + ne;
      int pb = (cbase >> 3) ^ (n & 7);
      U2 pk;
      pk.h[0] = f2bf(((const float*)&v[0])[ne] * wcs[0] + bcs[0]);
      pk.h[1] = f2bf(((const float*)&v[1])[ne] * wcs[1] + bcs[1]);
      pk.h[2] = f2bf(((const float*)&v[2])[ne] * wcs[2] + bcs[2]);
      pk.h[3] = f2bf(((const float*)&v[3])[ne] * wcs[3] + bcs[3]);
      *(uint2*)&T2[n * 72 + (pb << 3) + (cbase & 7)] = pk.v;
    }
  }
  __syncthreads();
  #pragma unroll
  for (int j = 0; j < 4; ++j) {
    int idx = j * 256 + t;
    int row = idx >> 3, cs = (idx & 7) * 8;
    uint4 vv = *(const uint4*)&T2[row * 72 + cs];
    *(uint4*)(hT + ((size_t)batch * 1024 + nt * 128 + row) * 512 + g * 64 + cs) = vv;
  }
}

// ---------------- KV GEMM body, 64x32 tiles ----------------
// blk in [0,1024): b = blk>>6, m0 = ((blk>>5)&1)*64, n0 = (blk&31)*32
__device__ void kvgemm_body(int blk, const u16* __restrict__ A, const u16* __restrict__ Bw,
                            const float* __restrict__ bias,
                            u16* __restrict__ o16a, u16* __restrict__ o16b,
                            u16* __restrict__ SH) {
  u16* As = SH;            // 64*64
  u16* Bs = SH + 4096;     // 32*64
  int t = threadIdx.x;
  int b = blk >> 6;
  int m0 = ((blk >> 5) & 1) * 64;
  int n0 = (blk & 31) * 32;
  const u16* aBase = A + (size_t)b * 98304 + (size_t)(m0 + (t >> 3)) * 768 + (t & 7) * 8;
  const u16* bBase = Bw + (size_t)(n0 + (t >> 3)) * 768 + (t & 7) * 8;
  int wid = t >> 6, l = t & 63;
  int wr = wid & 1, wc = wid >> 1;
  int lr = l & 15, lg = l >> 4, xr = lr & 7;
  fx4 acc[2];
  acc[0] = (fx4){0.f, 0.f, 0.f, 0.f};
  acc[1] = (fx4){0.f, 0.f, 0.f, 0.f};

  for (int k0 = 0; k0 < 768; k0 += 64) {
    __syncthreads();
    #pragma unroll
    for (int i = 0; i < 2; ++i)
      gload16(aBase + k0 + (size_t)i * 32 * 768, As + i * 2048 + t * 8);
    gload16(bBase + k0, Bs + t * 8);
    __syncthreads();
    #pragma unroll
    for (int kk = 0; kk < 2; ++kk) {
      int lb = kk * 4 + lg;
      bfx8 bf = *(const bfx8*)&Bs[(wc * 16 + lr) * 64 + ((lb ^ xr) << 3)];
      #pragma unroll
      for (int mi = 0; mi < 2; ++mi) {
        bfx8 af = *(const bfx8*)&As[(wr * 32 + mi * 16 + lr) * 64 + ((lb ^ xr) << 3)];
        acc[mi] = __builtin_amdgcn_mfma_f32_16x16x32_bf16(af, bf, acc[mi], 0, 0, 0);
      }
    }
  }

  int o = n0 + wc * 16 + lr;
  float bb = bias[o];
  #pragma unroll
  for (int mi = 0; mi < 2; ++mi) {
    int sb = m0 + wr * 32 + mi * 16 + lg * 4;
    if (o < 512) {
      #pragma unroll
      for (int r = 0; r < 4; ++r) {
        int sidx = sb + r;
        if (sidx < 96) {
          int ob = (o & ~63) | (((((o >> 3) & 7) ^ (sidx & 7))) << 3) | (o & 7);
          o16a[(size_t)b * 49152 + (size_t)sidx * 512 + ob] = f2bf(acc[mi][r] + bb);
        }
      }
    } else if (sb < 96) {
      U2 pk;
      #pragma unroll
      for (int r = 0; r < 4; ++r)
        pk.h[r] = (sb + r < S_) ? f2bf(acc[mi][r] + bb) : (u16)0;
      *(uint2*)(o16b + (size_t)b * 49152 + (size_t)(o - 512) * 96 + sb) = pk.v;
    }
  }
}

// ---------------- merged mid kernel: gn_apply (blocks 0-1023) + kvgemm (1024-2047) ----------------
__global__ __launch_bounds__(256) void mid_kernel(const float* __restrict__ x,
                                                  const float* __restrict__ gn_w,
                                                  const float* __restrict__ gn_b,
                                                  const float2* __restrict__ gpart,
                                                  u16* __restrict__ hT,
                                                  const u16* __restrict__ ctx_bf,
                                                  const u16* __restrict__ kvw_bf,
                                                  const float* __restrict__ kv_b,
                                                  u16* __restrict__ kvT_k,
                                                  u16* __restrict__ kvV) {
  __shared__ u16 SH[9216];   // gn: T2[128*72]=9216; kv: As 4096 + Bs 2048 (fits)
  int bid = blockIdx.x;
  if (bid < 1024) gn_apply_body(bid, x, gn_w, gn_b, gpart, hT, SH);
  else            kvgemm_body(bid - 1024, ctx_bf, kvw_bf, kv_b, kvT_k, kvV, SH);
}

// ---------------- proj GEMM: 128x128, f32 out + residual (R10-proven) ----------------
__global__ __launch_bounds__(256) void gemm2_kernel(
    const u16* __restrict__ A, const u16* __restrict__ Bw,
    const float* __restrict__ bias, const float* __restrict__ resid,
    float* __restrict__ outf, int K, size_t strideA)
{
  __shared__ u16 As[128 * 64];
  __shared__ u16 Bs[128 * 64];
  int t = threadIdx.x;
  int b = blockIdx.z;
  int n0 = blockIdx.x * 128, m0 = blockIdx.y * 128;
  const u16* aBase = A + (size_t)b * strideA + (size_t)(m0 + (t >> 3)) * K + (t & 7) * 8;
  const u16* bBase = Bw + (size_t)(n0 + (t >> 3)) * K + (t & 7) * 8;
  int wid = t >> 6, l = t & 63;
  int wr = wid >> 1, wc = wid & 1;
  int lr = l & 15, lg = l >> 4;
  fx4 acc[4][4];
  #pragma unroll
  for (int i = 0; i < 4; ++i)
    #pragma unroll
    for (int j = 0; j < 4; ++j) acc[i][j] = (fx4){0.f, 0.f, 0.f, 0.f};

  for (int k0 = 0; k0 < K; k0 += 64) {
    __syncthreads();
    #pragma unroll
    for (int i = 0; i < 4; ++i) {
      gload16(aBase + k0 + (size_t)i * 32 * K, As + i * 2048 + t * 8);
      gload16(bBase + k0 + (size_t)i * 32 * K, Bs + i * 2048 + t * 8);
    }
    __syncthreads();
    #pragma unroll
    for (int kk = 0; kk < 2; ++kk) {
      bfx8 af[4], bf[4];
      int xr = (lr & 7);
      #pragma unroll
      for (int i = 0; i < 4; ++i) {
        int lb = kk * 4 + lg;
        af[i] = *(const bfx8*)&As[(wr * 64 + i * 16 + lr) * 64 + ((lb ^ xr) << 3)];
        bf[i] = *(const bfx8*)&Bs[(wc * 64 + i * 16 + lr) * 64 + ((lb ^ xr) << 3)];
      }
      #pragma unroll
      for (int mi = 0; mi < 4; ++mi)
        #pragma unroll
        for (int ni = 0; ni < 4; ++ni)
          acc[mi][ni] = __builtin_amdgcn_mfma_f32_16x16x32_bf16(af[mi], bf[ni], acc[mi][ni], 0, 0, 0);
    }
  }

  float* O = outf + (size_t)b * 524288;
  const float* R = resid + (size_t)b * 524288;
  #pragma unroll
  for (int ni = 0; ni < 4; ++ni) {
    int cc = n0 + wc * 64 + ni * 16 + lr;
    float bb = bias[cc];
    #pragma unroll
    for (int mi = 0; mi < 4; ++mi) {
      size_t off = (size_t)cc * 1024 + m0 + wr * 64 + mi * 16 + lg * 4;
      float4 rv = *(const float4*)(R + off);
      float4 ov;
      ov.x = acc[mi][ni][0] + bb + rv.x;
      ov.y = acc[mi][ni][1] + bb + rv.y;
      ov.z = acc[mi][ni][2] + bb + rv.z;
      ov.w = acc[mi][ni][3] + bb + rv.w;
      *(float4*)(O + off) = ov;
    }
  }
}

// ---------------- fused Q-GEMM (LDS-staged) + attention (direct K/V), 64-q blocks ----------------
// hT: [b][n][512] swz; qw: [512][512] swz; kvK: [b][96][512] swz; kvV: [b][512][96] plain
// aoT out: [b][n][512] swz. LDS: QO 8KB + union{As 8KB + Bs 8KB, Ps 13.3KB} = 24KB -> 6 blocks/CU.
__global__ __launch_bounds__(256) void qattn_kernel(const u16* __restrict__ hT,
                                                    const u16* __restrict__ qw,
                                                    const float* __restrict__ q_b,
                                                    const u16* __restrict__ kvK,
                                                    const u16* __restrict__ kvV,
                                                    u16* __restrict__ aoT) {
  __shared__ u16 SH[12288];
  u16* QO = SH;                  // 64*64
  u16* As = SH + 4096;           // 64*64 staging (Q-GEMM phase)
  u16* Bs = SH + 8192;           // 64*64 staging
  u16* Ps = SH + 4096;           // 64*104 softmax weights (after Q-GEMM)

  int t = threadIdx.x;
  int n0 = blockIdx.x * 64, head = blockIdx.y, b = blockIdx.z;
  int wid = t >> 6, l = t & 63;
  int lr = l & 15, lg = l >> 4, xr = lr & 7;
  int qbase = wid * 16;

  // ---- Q-GEMM: QO[64 q][64 d] = hT[n0+q][:] . qw[head*64+d][:] + q_b (LDS-staged) ----
  {
    const u16* aBase = hT + (size_t)b * 524288 + (size_t)(n0 + (t >> 3)) * 512 + (t & 7) * 8;
    const u16* bBase = qw + (size_t)(head * 64 + (t >> 3)) * 512 + (t & 7) * 8;
    fx4 acc[4];
    #pragma unroll
    for (int j = 0; j < 4; ++j) acc[j] = (fx4){0.f, 0.f, 0.f, 0.f};
    for (int k0 = 0; k0 < 512; k0 += 64) {
      __syncthreads();
      #pragma unroll
      for (int i = 0; i < 2; ++i) {
        gload16(aBase + k0 + (size_t)i * 32 * 512, As + i * 2048 + t * 8);
        gload16(bBase + k0 + (size_t)i * 32 * 512, Bs + i * 2048 + t * 8);
      }
      __syncthreads();
      #pragma unroll
      for (int kk = 0; kk < 2; ++kk) {
        int lb = kk * 4 + lg;
        bfx8 af = *(const bfx8*)&As[(qbase + lr) * 64 + ((lb ^ xr) << 3)];
        bfx8 bf[4];
        #pragma unroll
        for (int i = 0; i < 4; ++i)
          bf[i] = *(const bfx8*)&Bs[(i * 16 + lr) * 64 + ((lb ^ xr) << 3)];
        #pragma unroll
        for (int ni = 0; ni < 4; ++ni)
          acc[ni] = __builtin_amdgcn_mfma_f32_16x16x32_bf16(af, bf[ni], acc[ni], 0, 0, 0);
      }
    }
    // scatter D+bias into QO (swizzled [q][d]); own-wave rows only
    #pragma unroll
    for (int ni = 0; ni < 4; ++ni) {
      int d = ni * 16 + lr;
      float bb = q_b[head * 64 + d];
      #pragma unroll
      for (int r = 0; r < 4; ++r) {
        int q = qbase + lg * 4 + r;
        QO[q * 64 + ((((d >> 3) ^ (q & 7))) << 3) + (d & 7)] = f2bf(acc[ni][r] + bb);
      }
    }
  }
  __syncthreads();   // all waves done reading As/Bs -> Ps region usable

  // ---- zero Ps pad cols [80,96) for own-wave rows ----
  {
    int row = qbase + (l >> 2), part = l & 3;
    if (part < 2)
      *(uint4*)&Ps[row * 104 + 80 + part * 8] = (uint4){0u, 0u, 0u, 0u};
  }

  // ---- QK^T + softmax + P (K direct from global, L1/L2-resident slice) ----
  const u16* kB = kvK + (size_t)b * 49152 + head * 64;
  {
    int qrow = qbase + lr;
    fx4 sc[5];
    #pragma unroll
    for (int ti = 0; ti < 5; ++ti) sc[ti] = (fx4){0.f, 0.f, 0.f, 0.f};
    #pragma unroll
    for (int ks = 0; ks < 2; ++ks) {
      int kb = ((ks * 4 + lg) ^ xr) << 3;
      bfx8 a = *(const bfx8*)&QO[qrow * 64 + kb];
      #pragma unroll
      for (int ti = 0; ti < 5; ++ti) {
        bfx8 bb = *(const bfx8*)(kB + (size_t)(ti * 16 + lr) * 512 + kb);
        sc[ti] = __builtin_amdgcn_mfma_f32_16x16x32_bf16(a, bb, sc[ti], 0, 0, 0);
      }
    }
    #pragma unroll
    for (int ti = 0; ti < 5; ++ti) {
      bool valid = (ti * 16 + lr) < S_;
      #pragma unroll
      for (int r = 0; r < 4; ++r)
        sc[ti][r] = valid ? sc[ti][r] * 0.125f : -1e30f;
    }
    fx4 mx = sc[0];
    #pragma unroll
    for (int ti = 1; ti < 5; ++ti)
      #pragma unroll
      for (int r = 0; r < 4; ++r) mx[r] = fmaxf(mx[r], sc[ti][r]);
    #pragma unroll
    for (int off = 1; off < 16; off <<= 1)
      #pragma unroll
      for (int r = 0; r < 4; ++r) mx[r] = fmaxf(mx[r], __shfl_xor(mx[r], off));
    fx4 sm = (fx4){0.f, 0.f, 0.f, 0.f};
    #pragma unroll
    for (int ti = 0; ti < 5; ++ti)
      #pragma unroll
      for (int r = 0; r < 4; ++r) {
        float e = __expf(sc[ti][r] - mx[r]);
        sc[ti][r] = e; sm[r] += e;
      }
    #pragma unroll
    for (int off = 1; off < 16; off <<= 1)
      #pragma unroll
      for (int r = 0; r < 4; ++r) sm[r] += __shfl_xor(sm[r], off);
    // hoist reciprocal: 4 v_rcp_f32 instead of 20 full-precision divides
    fx4 inv;
    #pragma unroll
    for (int r = 0; r < 4; ++r) inv[r] = __builtin_amdgcn_rcpf(sm[r]);
    #pragma unroll
    for (int ti = 0; ti < 5; ++ti)
      #pragma unroll
      for (int r = 0; r < 4; ++r)
        Ps[(qbase + lg * 4 + r) * 104 + ti * 16 + lr] = f2bf(sc[ti][r] * inv[r]);
  }

  // ---- PV (A = V direct from global [d][96], B = P from LDS) -> D[d][q] ----
  const u16* vB = kvV + (size_t)b * 49152 + (size_t)head * 64 * 96;
  {
    int q = qbase + lr;
    fx4 o[4];
    #pragma unroll
    for (int dt = 0; dt < 4; ++dt) o[dt] = (fx4){0.f, 0.f, 0.f, 0.f};
    #pragma unroll
    for (int ks = 0; ks < 3; ++ks) {
      bfx8 pb_ = *(const bfx8*)&Ps[q * 104 + ks * 32 + lg * 8];
      #pragma unroll
      for (int dt = 0; dt < 4; ++dt) {
        bfx8 a = *(const bfx8*)(vB + (size_t)(dt * 16 + lr) * 96 + ks * 32 + lg * 8);
        o[dt] = __builtin_amdgcn_mfma_f32_16x16x32_bf16(a, pb_, o[dt], 0, 0, 0);
      }
    }
    #pragma unroll
    for (int dt = 0; dt < 4; ++dt) {
      int db = dt * 16 + lg * 4;
      int pb = ((db >> 3) ^ (q & 7));
      U2 pk;
      #pragma unroll
      for (int r = 0; r < 4; ++r) pk.h[r] = f2bf(o[dt][r]);
      *(uint2*)&QO[q * 64 + (pb << 3) + (db & 7)] = pk.v;
    }
  }
  __syncthreads();

  const size_t aobase = (size_t)b * 524288 + (size_t)n0 * 512 + head * 64;
  #pragma unroll
  for (int j = 0; j < 2; ++j) {
    int idx = j * 256 + t;
    int row = idx >> 3, cs = (idx & 7) * 8;
    *(uint4*)(aoT + aobase + (size_t)row * 512 + cs) = *(const uint4*)&QO[row * 64 + cs];
  }
}

extern "C" void kernel_launch(void* const* d_in, const int* in_sizes, int n_in,
                              void* d_out, int out_size, void* d_ws, size_t ws_size,
                              hipStream_t stream) {
  const float* x      = (const float*)d_in[0];
  const float* ctx    = (const float*)d_in[1];
  const float* gn_w   = (const float*)d_in[2];
  const float* gn_b   = (const float*)d_in[3];
  const float* q_w    = (const float*)d_in[4];
  const float* q_b    = (const float*)d_in[5];
  const float* kv_w   = (const float*)d_in[6];
  const float* kv_b   = (const float*)d_in[7];
  const float* proj_w = (const float*)d_in[8];
  const float* proj_b = (const float*)d_in[9];
  float* out = (float*)d_out;

  u16* p = (u16*)d_ws;
  u16* qw_bf  = p; p += 262144;          // 512*512
  u16* kvw_bf = p; p += 786432;          // 1024*768
  u16* pjw_bf = p; p += 262144;          // 512*512
  u16* ctx_bf = p; p += 16 * 128 * 768;  // padded rows
  u16* hT     = p; p += 8388608;         // 16*1024*512
  u16* aoT    = p; p += 8388608;         // 16*1024*512
  u16* kvT_k  = p; p += 16 * 96 * 512;
  u16* kvV    = p; p += 16 * 512 * 96;   // V [d][96], zero-padded
  float2* gpart = (float2*)p; p += 1024 * 4;

  // 1) fused prep: 3 weight casts + ctx cast + GN partial sums
  prep_kernel<<<3228, 256, 0, stream>>>(q_w, kv_w, proj_w, ctx, x,
                                        qw_bf, kvw_bf, pjw_bf, ctx_bf, gpart);

  // 2) merged: GN apply (blocks 0-1023) + KV GEMM (blocks 1024-2047) — independent, co-resident
  mid_kernel<<<2048, 256, 0, stream>>>(x, gn_w, gn_b, gpart, hT,
                                       ctx_bf, kvw_bf, kv_b, kvT_k, kvV);

  // 3) fused Q-GEMM (staged) + attention (direct K/V), 64-q blocks for occupancy
  qattn_kernel<<<dim3(16, HEADS_, B_), 256, 0, stream>>>(hT, qw_bf, q_b, kvT_k, kvV, aoT);

  // 4) proj: 128x128 -> f32 out + residual
  gemm2_kernel<<<dim3(4, 8, B_), 256, 0, stream>>>(
      aoT, pjw_bf, proj_b, x, out, 512, (size_t)1024 * 512);
}